// Round 5
// baseline (229.372 us; speedup 1.0000x reference)
//
#include <hip/hip_runtime.h>

// Sparsemax, last dim d=1024, 32768 rows, fp32. One wave per row, 16
// register-resident elements/lane. Zero DS-pipe traffic (DPP reductions).
//
// tau* in [max-1, max), so only elements z > max-1 matter for the Newton
// iteration t' = t + (sum(relu(z-t)) - 1)/#{z>t}. Each lane collapses its
// 16 elements to <=3 register candidates (E[cands/lane] ~ 0.22); rows where
// any lane overflows (P ~ 0.5%) take a wave-uniform full-row fallback.

#define ROW_D 1024
#define NEG_PAD -3.0e38f

typedef float f4 __attribute__((ext_vector_type(4)));

template <int CTRL, int RMASK>
__device__ __forceinline__ float dpp_mv(float x) {
    return __builtin_bit_cast(float, __builtin_amdgcn_update_dpp(
        __builtin_bit_cast(int, x), __builtin_bit_cast(int, x),
        CTRL, RMASK, 0xf, false));
}
// Wave64 reduce -> lane 63 (row_shr folds 16-lane rows, bcast15/31 fold rows).
__device__ __forceinline__ float dpp_sum_to63(float x) {
    x += dpp_mv<0x111, 0xf>(x);
    x += dpp_mv<0x112, 0xf>(x);
    x += dpp_mv<0x114, 0xf>(x);
    x += dpp_mv<0x118, 0xf>(x);
    x += dpp_mv<0x142, 0xa>(x);
    x += dpp_mv<0x143, 0xc>(x);
    return x;
}
__device__ __forceinline__ float dpp_max_to63(float x) {
    x = fmaxf(x, dpp_mv<0x111, 0xf>(x));
    x = fmaxf(x, dpp_mv<0x112, 0xf>(x));
    x = fmaxf(x, dpp_mv<0x114, 0xf>(x));
    x = fmaxf(x, dpp_mv<0x118, 0xf>(x));
    x = fmaxf(x, dpp_mv<0x142, 0xa>(x));
    x = fmaxf(x, dpp_mv<0x143, 0xc>(x));
    return x;
}
__device__ __forceinline__ float bcast63(float x) {
    return __builtin_bit_cast(float,
        __builtin_amdgcn_readlane(__builtin_bit_cast(int, x), 63));
}

__global__ __launch_bounds__(256) void sparsemax_kernel(
    const float* __restrict__ z, float* __restrict__ out, int nrows) {
    const int lane = (int)(threadIdx.x & 63u);
    const int row  = (int)(blockIdx.x << 2) + (int)(threadIdx.x >> 6);
    if (row >= nrows) return;

    const f4* __restrict__ zin = reinterpret_cast<const f4*>(z + (size_t)row * ROW_D);
    f4* __restrict__ pout      = reinterpret_cast<f4*>(out + (size_t)row * ROW_D);

    // 16 elements/lane, 4 coalesced dwordx4 loads.
    f4 v[4];
#pragma unroll
    for (int j = 0; j < 4; ++j) v[j] = zin[lane + 64 * j];

    // Row max via register tree + DPP wave-max.
    float mj[4];
#pragma unroll
    for (int j = 0; j < 4; ++j)
        mj[j] = fmaxf(fmaxf(v[j].x, v[j].y), fmaxf(v[j].z, v[j].w));
    float m = fmaxf(fmaxf(mj[0], mj[1]), fmaxf(mj[2], mj[3]));
    m = bcast63(dpp_max_to63(m));
    const float lo0 = m - 1.0f;

    // Per-lane collapse: keep up to 3 candidates e > lo0 in registers.
    float c0 = NEG_PAD, c1 = NEG_PAD, c2 = NEG_PAD;
    int cnt = 0;
#pragma unroll
    for (int j = 0; j < 4; ++j) {
        const float e[4] = {v[j].x, v[j].y, v[j].z, v[j].w};
#pragma unroll
        for (int c = 0; c < 4; ++c) {
            const bool g = e[c] > lo0;           // predicated shift-insert
            c2 = g ? c1 : c2;
            c1 = g ? c0 : c1;
            c0 = g ? e[c] : c0;
            cnt += g ? 1 : 0;
        }
    }

    float t = lo0;
    if (__ballot(cnt > 3) == 0ULL) {
        // Fast path: Newton on <=3 candidates/lane. Monotone from below,
        // exact on the root's linear segment; wave-uniform early exit.
#pragma unroll 1
        for (int it = 0; it < 16; ++it) {
            const float d0 = c0 - t, d1 = c1 - t, d2 = c2 - t;
            const float s = fmaxf(d0, 0.0f) + (fmaxf(d1, 0.0f) + fmaxf(d2, 0.0f));
            int n = __popcll(__ballot(d0 > 0.0f));
            n += __popcll(__ballot(d1 > 0.0f));
            n += __popcll(__ballot(d2 > 0.0f));
            const float S = bcast63(dpp_sum_to63(s));
            const float t2 = t + (S - 1.0f) / (float)n;   // n>=1: t < max
            if (t2 - t <= 1e-6f) { t = t2; break; }        // wave-uniform
            t = t2;
        }
    } else {
        // Fallback (~0.5% of rows): Newton over all 16 elements/lane.
#pragma unroll 1
        for (int it = 0; it < 24; ++it) {
            float sj[4];
            int n = 0;
#pragma unroll
            for (int j = 0; j < 4; ++j) {
                const float d0 = v[j].x - t, d1 = v[j].y - t;
                const float d2 = v[j].z - t, d3 = v[j].w - t;
                sj[j] = (fmaxf(d0, 0.0f) + fmaxf(d1, 0.0f)) +
                        (fmaxf(d2, 0.0f) + fmaxf(d3, 0.0f));
                n += __popcll(__ballot(d0 > 0.0f));
                n += __popcll(__ballot(d1 > 0.0f));
                n += __popcll(__ballot(d2 > 0.0f));
                n += __popcll(__ballot(d3 > 0.0f));
            }
            const float S = bcast63(dpp_sum_to63((sj[0] + sj[1]) + (sj[2] + sj[3])));
            const float t2 = t + (S - 1.0f) / (float)n;
            if (t2 - t <= 1e-6f) { t = t2; break; }
            t = t2;
        }
    }

    // p = relu(z - tau); nontemporal stores (output never re-read).
#pragma unroll
    for (int j = 0; j < 4; ++j) {
        f4 o;
        o.x = fmaxf(v[j].x - t, 0.0f);
        o.y = fmaxf(v[j].y - t, 0.0f);
        o.z = fmaxf(v[j].z - t, 0.0f);
        o.w = fmaxf(v[j].w - t, 0.0f);
        __builtin_nontemporal_store(o, pout + lane + 64 * j);
    }
}

extern "C" void kernel_launch(void* const* d_in, const int* in_sizes, int n_in,
                              void* d_out, int out_size, void* d_ws, size_t ws_size,
                              hipStream_t stream) {
    const float* z = (const float*)d_in[0];
    float* out = (float*)d_out;
    const int n = in_sizes[0];        // 8*4096*1024
    const int nrows = n / ROW_D;      // 32768
    const int blocks = (nrows + 3) / 4;   // 4 rows (waves) per 256-thread block
    sparsemax_kernel<<<blocks, 256, 0, stream>>>(z, out, nrows);
}